// Round 24
// baseline (954.879 us; speedup 1.0000x reference)
//
#include <hip/hip_runtime.h>
#include <hip/hip_bf16.h>
#include <math.h>

// RWKV7 attention, round 24 (= round 23 with the two merge races fixed):
//  - WL (padded LoRA-A weights) relocated W0 -> W6 (mega_b raced R-write vs WL-read).
//  - YA relocated W5 -> W4, KK out W4 -> W5 (mega_c raced YA-write vs v-mix read).
//  - ka_epi / scan argument windows swapped to match. Math bit-identical to r22 (829us).

typedef __attribute__((ext_vector_type(8))) unsigned short ushort8;
typedef __attribute__((ext_vector_type(8))) _Float16 f16x8;
typedef __attribute__((ext_vector_type(4))) float f32x4;
typedef __attribute__((ext_vector_type(2))) float f32x2;

__device__ inline unsigned short f2h(float f) {
    _Float16 h = (_Float16)f;
    return __builtin_bit_cast(unsigned short, h);
}
__device__ inline float h2f(unsigned short u) {
    return (float)__builtin_bit_cast(_Float16, u);
}
__device__ inline float sigm(float x) { return 1.f / (1.f + expf(-x)); }

template <int CTRL>
__device__ __forceinline__ float rrot(float x) {
    int xi = __builtin_bit_cast(int, x);
    int yi = __builtin_amdgcn_update_dpp(xi, xi, CTRL, 0xf, 0xf, true);
    return x + __builtin_bit_cast(float, yi);
}
__device__ __forceinline__ float red8(float x)  { return rrot<0x128>(x); }
__device__ __forceinline__ float red16(float x) {
    float b = x;
    asm("" : "+v"(b));
    float a = x;
    asm("v_permlane16_swap_b32 %0, %1" : "+v"(a), "+v"(b));
    return a + b;
}
__device__ __forceinline__ float red32(float x) {
    float b = x;
    asm("" : "+v"(b));
    float a = x;
    asm("v_permlane32_swap_b32 %0, %1" : "+v"(a), "+v"(b));
    return a + b;
}
__device__ __forceinline__ float full64(float x) {
    x = rrot<0x121>(x);
    x = rrot<0x122>(x);
    x = rrot<0x124>(x);
    x = rrot<0x128>(x);
    return red32(red16(x));
}

__device__ __forceinline__ void gld16(void* lds, const void* g)
{
    __builtin_amdgcn_global_load_lds(
        (const __attribute__((address_space(1))) void*)g,
        (__attribute__((address_space(3))) void*)lds, 16, 0, 0);
}
__device__ __forceinline__ void gld4(void* lds, const void* g)
{
    __builtin_amdgcn_global_load_lds(
        (const __attribute__((address_space(1))) void*)g,
        (__attribute__((address_space(3))) void*)lds, 4, 0, 0);
}

// ---- shared fp16 GEMM inner loop (128x128 tile, K-step 32, gld16 staging) ----
__device__ __forceinline__ void gemm128_loop(
    const unsigned short* __restrict__ Ag, const unsigned short* __restrict__ Bg,
    unsigned short* As, unsigned short* Bhs,
    int m0, int n0, int K, int tid, f32x4 (&acc)[4][4])
{
    const int wave = tid >> 6, lane = tid & 63;
    const int wr = (wave >> 1) * 64, wc = (wave & 1) * 64;
    const int fr = lane & 15, fq = lane >> 4;

    const unsigned short* gsrc;
    unsigned short* lbuf;
    int rofs, nld;
    if (wave == 0)      { gsrc = Ag; lbuf = As;           rofs = m0;      nld = 4; }
    else if (wave == 1) { gsrc = Ag; lbuf = As + 64 * 32; rofs = m0 + 64; nld = 4; }
    else if (wave == 2) { gsrc = Bg; lbuf = Bhs;          rofs = n0;      nld = 8; }
    else                { gsrc = Bg; lbuf = Bhs;          rofs = n0;      nld = 0; }
    const unsigned short* gbase = gsrc + (size_t)(rofs + (lane >> 2)) * K + ((lane & 3) << 3);

    for (int k0 = 0; k0 < K; k0 += 32) {
        #pragma unroll
        for (int j = 0; j < 8; ++j)
            if (j < nld)
                gld16(lbuf + j * 16 * 32, gbase + (size_t)(j * 16) * K + k0);
        __syncthreads();

        f16x8 fa[4], fb[4];
        #pragma unroll
        for (int m = 0; m < 4; ++m)
            fa[m] = *(const f16x8*)&As[(wr + m * 16 + fr) * 32 + fq * 8];
        #pragma unroll
        for (int n = 0; n < 4; ++n)
            fb[n] = *(const f16x8*)&Bhs[(wc + n * 16 + fr) * 32 + fq * 8];
        #pragma unroll
        for (int m = 0; m < 4; ++m)
            #pragma unroll
            for (int n = 0; n < 4; ++n)
                acc[m][n] = __builtin_amdgcn_mfma_f32_16x16x32_f16(fa[m], fb[n], acc[m][n], 0, 0, 0);
        __syncthreads();
    }
}

#define GBM 128
#define GBN 128

// ================= mega_prep: mixes + LoRA-A pad + six weight converts ===========
__global__ __launch_bounds__(256) void mega_prep(
    const float* __restrict__ in, const float* __restrict__ x_x,
    unsigned short* __restrict__ oR, unsigned short* __restrict__ oK,
    unsigned short* __restrict__ ow, unsigned short* __restrict__ oa,
    unsigned short* __restrict__ og, unsigned short* __restrict__ ov,
    const float* __restrict__ wA, const float* __restrict__ vA,
    const float* __restrict__ aA, const float* __restrict__ gA,
    unsigned short* __restrict__ WL,
    const float* __restrict__ Wr, const float* __restrict__ Wk,
    const float* __restrict__ Wv, const float* __restrict__ wB,
    const float* __restrict__ aB, const float* __restrict__ gB,
    unsigned short* __restrict__ oWr, unsigned short* __restrict__ oWk,
    unsigned short* __restrict__ oWv, unsigned short* __restrict__ owB,
    unsigned short* __restrict__ oaB, unsigned short* __restrict__ ogB,
    int T, int D, int nMix, int nBig, int nSm, int nG)
{
    const int bid = blockIdx.x;
    const int tid = threadIdx.x;

    if (bid < 4096) {                       // ---- mixcvt6 ----
        int i = bid * 256 + tid;
        if (i >= nMix) return;
        const size_t e = (size_t)i * 8;
        float a[8];
        *(float4*)&a[0] = *(const float4*)(in + e);
        *(float4*)&a[4] = *(const float4*)(in + e + 4);
        const int m = (int)(e / D);
        const int d = (int)(e % D);
        const int t = m % T;
        float p[8] = {0.f,0.f,0.f,0.f,0.f,0.f,0.f,0.f};
        if (t > 0) {
            *(float4*)&p[0] = *(const float4*)(in + e - D);
            *(float4*)&p[4] = *(const float4*)(in + e - D + 4);
        }
        const float* xxr = x_x + 0 * (size_t)D + d;
        const float* xxw = x_x + 1 * (size_t)D + d;
        const float* xxk = x_x + 2 * (size_t)D + d;
        const float* xxv = x_x + 3 * (size_t)D + d;
        const float* xxa = x_x + 4 * (size_t)D + d;
        const float* xxg = x_x + 5 * (size_t)D + d;
        ushort8 rr, rk, rw, ra, rg, rv;
        #pragma unroll
        for (int j = 0; j < 8; ++j) {
            const float dl = p[j] - a[j];
            rr[j] = f2h(a[j] + dl * xxr[j]);
            rk[j] = f2h(a[j] + dl * xxk[j]);
            rw[j] = f2h(a[j] + dl * xxw[j]);
            ra[j] = f2h(a[j] + dl * xxa[j]);
            rg[j] = f2h(a[j] + dl * xxg[j]);
            rv[j] = f2h(a[j] + dl * xxv[j]);
        }
        *(ushort8*)(oR + e) = rr;
        *(ushort8*)(oK + e) = rk;
        *(ushort8*)(ow + e) = rw;
        *(ushort8*)(oa + e) = ra;
        *(ushort8*)(og + e) = rg;
        *(ushort8*)(ov + e) = rv;
        return;
    }
    if (bid < 4608) {                       // ---- wcvt_lora ----
        const int b2 = bid - 4096;
        const int z = b2 >> 7;
        int i = (b2 & 127) * 256 + tid;
        const size_t e = (size_t)i * 8;
        const int row = (int)(e / D);
        const int col = (int)(e % D);
        const int nv = (z == 0) ? 64 : (z == 1) ? 16 : (z == 2) ? 64 : 128;
        const float* src = (z == 0) ? wA : (z == 1) ? vA : (z == 2) ? aA : gA;
        ushort8 h8;
        if (row < nv) {
            float a[8];
            *(float4*)&a[0] = *(const float4*)(src + (size_t)row * D + col);
            *(float4*)&a[4] = *(const float4*)(src + (size_t)row * D + col + 4);
            #pragma unroll
            for (int j = 0; j < 8; ++j) h8[j] = f2h(a[j]);
        } else {
            #pragma unroll
            for (int j = 0; j < 8; ++j) h8[j] = 0;
        }
        *(ushort8*)(WL + (size_t)z * 128 * D + e) = h8;
        return;
    }
    // ---- weight converts ----
    int b2 = bid - 4608;
    const float* win;
    unsigned short* hi;
    int i, lim;
    if (b2 < 2048)                { win = Wr; hi = oWr; i = b2 * 256 + tid;         lim = nBig; }
    else if ((b2 -= 2048) < 2048) { win = Wk; hi = oWk; i = b2 * 256 + tid;         lim = nBig; }
    else if ((b2 -= 2048) < 2048) { win = Wv; hi = oWv; i = b2 * 256 + tid;         lim = nBig; }
    else if ((b2 -= 2048) < 64)   { win = wB; hi = owB; i = b2 * 256 + tid;         lim = nSm; }
    else if ((b2 -= 64) < 64)     { win = aB; hi = oaB; i = b2 * 256 + tid;         lim = nSm; }
    else                          { win = gB; hi = ogB; i = (b2 - 64) * 256 + tid;  lim = nG; }
    if (i >= lim) return;
    const size_t e = (size_t)i * 8;
    float a[8];
    *(float4*)&a[0] = *(const float4*)(win + e);
    *(float4*)&a[4] = *(const float4*)(win + e + 4);
    ushort8 h8;
    #pragma unroll
    for (int j = 0; j < 8; ++j) h8[j] = f2h(a[j]);
    *(ushort8*)(hi + e) = h8;
}

// ================= mega_b: R/K projections + LoRA stage-1 ======================
// Writes: W0 (R), W2 (K), SMALL (HW16/HV/HA16/HG16). Reads: W1 (X2), W3 (WRK),
// W4/W5 (X4 mixes), W6 (WL). All disjoint.
__global__ __launch_bounds__(256) void mega_b(
    const unsigned short* __restrict__ Xrk,
    const unsigned short* __restrict__ Wr16, const unsigned short* __restrict__ Wk16,
    float* __restrict__ Cr, float* __restrict__ Ck,
    const unsigned short* __restrict__ X4, const unsigned short* __restrict__ WL,
    unsigned short* __restrict__ HW16, float* __restrict__ HV,
    unsigned short* __restrict__ HA16, unsigned short* __restrict__ HG16,
    int M, int D, size_t NE)
{
    __shared__ unsigned short As[GBM * 32];
    __shared__ unsigned short Bhs[GBN * 32];
    const int bid = blockIdx.x;
    const int tid = threadIdx.x;
    const int wave = tid >> 6, lane = tid & 63;
    const int wr = (wave >> 1) * 64, wc = (wave & 1) * 64;
    const int fr = lane & 15, fq = lane >> 4;

    f32x4 acc[4][4];
    #pragma unroll
    for (int i = 0; i < 4; ++i)
        #pragma unroll
        for (int j = 0; j < 4; ++j)
            acc[i][j] = (f32x4){0.f, 0.f, 0.f, 0.f};

    if (bid < 1024) {                       // ---- R/K ----
        const int z = bid >> 9;
        const int m0 = ((bid & 511) >> 4) * GBM;
        const int n0 = (bid & 15) * GBN;
        const unsigned short* Ag = Xrk + (size_t)z * NE;
        const unsigned short* Bg = (z == 0) ? Wr16 : Wk16;
        float* C = (z == 0) ? Cr : Ck;
        gemm128_loop(Ag, Bg, As, Bhs, m0, n0, D, tid, acc);
        #pragma unroll
        for (int m = 0; m < 4; ++m) {
            const int row = m0 + wr + m * 16 + fq * 4;
            #pragma unroll
            for (int n = 0; n < 4; ++n) {
                const int col = n0 + wc + n * 16 + fr;
                #pragma unroll
                for (int j = 0; j < 4; ++j)
                    C[(size_t)(row + j) * D + col] = acc[m][n][j];
            }
        }
        return;
    }
    // ---- lora1 ----
    {
        const int b2 = bid - 1024;
        const int z = b2 >> 5;
        const int m0 = (b2 & 31) * GBM;
        const size_t zofs = (z == 0) ? 0 : (z == 1) ? 3 * NE : (z == 2) ? NE : 2 * NE;  // w,v,a,g
        const unsigned short* Ag = X4 + zofs;
        const unsigned short* Bg = WL + (size_t)z * 128 * D;
        gemm128_loop(Ag, Bg, As, Bhs, m0, 0, D, tid, acc);
        #pragma unroll
        for (int m = 0; m < 4; ++m) {
            const int row = m0 + wr + m * 16 + fq * 4;
            #pragma unroll
            for (int n = 0; n < 4; ++n) {
                const int col = wc + n * 16 + fr;
                #pragma unroll
                for (int j = 0; j < 4; ++j) {
                    const float v = acc[m][n][j];
                    const int r = row + j;
                    if (z == 0)      { if (col < 64) HW16[(size_t)r * 64 + col] = f2h(tanhf(v)); }
                    else if (z == 1) { if (col < 16) HV[(size_t)r * 16 + col] = v; }
                    else if (z == 2) { if (col < 64) HA16[(size_t)r * 64 + col] = f2h(v); }
                    else             { HG16[(size_t)r * 128 + col] = f2h(sigm(v)); }
                }
            }
        }
    }
}

// ================= mega_c: V projection (inline-yv lerp) + LoRA stage-2 =========
// Writes: W3 (Vf), W1 (EW), W4 (YA). Reads: W5-upper (v mix), W6 (Wv16/wB16/aB16),
// SMALL (HV/HW16/HA16). All disjoint.
__global__ __launch_bounds__(256) void mega_c(
    const unsigned short* __restrict__ Xv, const unsigned short* __restrict__ Wv16,
    float* __restrict__ Cv,
    const float* __restrict__ HVp, const float* __restrict__ vBp,
    const float* __restrict__ vb, const float* __restrict__ vst,
    const unsigned short* __restrict__ HWA16,   // HW16 then HA16 (M*64 each)
    const unsigned short* __restrict__ waB16,   // wB16 then aB16 (D*64 each)
    float* __restrict__ EW, float* __restrict__ YA,
    const float* __restrict__ wb,
    int M, int D)
{
    __shared__ unsigned short As[GBM * 32];
    __shared__ unsigned short Bhs[GBN * 32];
    const int bid = blockIdx.x;
    const int tid = threadIdx.x;
    const int wave = tid >> 6, lane = tid & 63;
    const int wr = (wave >> 1) * 64, wc = (wave & 1) * 64;
    const int fr = lane & 15, fq = lane >> 4;

    f32x4 acc[4][4];
    #pragma unroll
    for (int i = 0; i < 4; ++i)
        #pragma unroll
        for (int j = 0; j < 4; ++j)
            acc[i][j] = (f32x4){0.f, 0.f, 0.f, 0.f};

    if (bid < 512) {                        // ---- V ----
        const int m0 = (bid >> 4) * GBM;
        const int n0 = (bid & 15) * GBN;
        gemm128_loop(Xv, Wv16, As, Bhs, m0, n0, D, tid, acc);
        #pragma unroll
        for (int m = 0; m < 4; ++m) {
            const int row = m0 + wr + m * 16 + fq * 4;
            #pragma unroll
            for (int n = 0; n < 4; ++n) {
                const int col = n0 + wc + n * 16 + fr;
                #pragma unroll
                for (int j = 0; j < 4; ++j) {
                    const size_t idx = (size_t)(row + j) * D + col;
                    float v = acc[m][n][j];
                    const float* hv = HVp + (size_t)(row + j) * 16;
                    const float* vv = vBp + (size_t)col * 16;
                    float yv = 0.f;
                    #pragma unroll
                    for (int kk = 0; kk < 16; ++kk) yv = fmaf(hv[kk], vv[kk], yv);
                    const float sg = sigm(yv + vb[col]);
                    Cv[idx] = v + sg * (vst[idx] - v);
                }
            }
        }
        return;
    }
    // ---- lora2 (K=64) ----
    {
        const int b2 = bid - 512;
        const int z = b2 >> 9;
        const int m0 = ((b2 & 511) >> 4) * GBM;
        const int n0 = (b2 & 15) * GBN;
        const unsigned short* Ag = HWA16 + (size_t)z * M * 64;
        const unsigned short* Bg = waB16 + (size_t)z * D * 64;
        float* C = (z == 0) ? EW : YA;
        gemm128_loop(Ag, Bg, As, Bhs, m0, n0, 64, tid, acc);
        #pragma unroll
        for (int m = 0; m < 4; ++m) {
            const int row = m0 + wr + m * 16 + fq * 4;
            #pragma unroll
            for (int n = 0; n < 4; ++n) {
                const int col = n0 + wc + n * 16 + fr;
                #pragma unroll
                for (int j = 0; j < 4; ++j) {
                    float v = acc[m][n][j];
                    if (z == 0) v = 0.6065306597126334f * sigm(v + wb[col]);
                    C[(size_t)(row + j) * D + col] = v;
                }
            }
        }
    }
}

// ---------------- generic fp16 GEMM (Wo projection + fallback path) ----------
template <int TERMS>
__global__ __launch_bounds__(256) void gemm_h2(
    const unsigned short* __restrict__ Ag,
    const unsigned short* __restrict__ Bhg, const unsigned short* __restrict__ Blg,
    float* __restrict__ C, int M, int N, int K, int mode,
    const float* __restrict__ HVp, const float* __restrict__ vBp,
    const float* __restrict__ bias, const float* __restrict__ aux,
    size_t sA, size_t sB, size_t sC)
{
    __shared__ unsigned short As[GBM * 32];
    __shared__ unsigned short Bhs[GBN * 32], Bls[GBN * 32];
    const int z = blockIdx.z;
    Ag  += (size_t)z * sA;
    Bhg += (size_t)z * sB;
    Blg += (size_t)z * sB;
    C   += (size_t)z * sC;
    const int tid = threadIdx.x;
    const int m0 = blockIdx.x * GBM;
    const int n0 = blockIdx.y * GBN;
    const int wave = tid >> 6, lane = tid & 63;
    const int wr = (wave >> 1) * 64, wc = (wave & 1) * 64;
    const int fr = lane & 15, fq = lane >> 4;

    f32x4 acc[4][4];
    #pragma unroll
    for (int i = 0; i < 4; ++i)
        #pragma unroll
        for (int j = 0; j < 4; ++j)
            acc[i][j] = (f32x4){0.f, 0.f, 0.f, 0.f};

    const unsigned short* gsrc;
    unsigned short* lbuf;
    int rofs, nld;
    if (wave == 0)      { gsrc = Ag;  lbuf = As;           rofs = m0;      nld = 4; }
    else if (wave == 1) { gsrc = Ag;  lbuf = As + 64 * 32; rofs = m0 + 64; nld = 4; }
    else if (wave == 2) { gsrc = Bhg; lbuf = Bhs;          rofs = n0;      nld = 8; }
    else                { gsrc = Blg; lbuf = Bls;          rofs = n0;      nld = (TERMS == 2) ? 8 : 0; }
    const unsigned short* gbase = gsrc + (size_t)(rofs + (lane >> 2)) * K + ((lane & 3) << 3);

    for (int k0 = 0; k0 < K; k0 += 32) {
        #pragma unroll
        for (int j = 0; j < 8; ++j)
            if (j < nld)
                gld16(lbuf + j * 16 * 32, gbase + (size_t)(j * 16) * K + k0);
        __syncthreads();

        f16x8 fa[4], fbh[4], fbl[4];
        #pragma unroll
        for (int m = 0; m < 4; ++m)
            fa[m] = *(const f16x8*)&As[(wr + m * 16 + fr) * 32 + fq * 8];
        #pragma unroll
        for (int n = 0; n < 4; ++n) {
            fbh[n] = *(const f16x8*)&Bhs[(wc + n * 16 + fr) * 32 + fq * 8];
            if constexpr (TERMS == 2)
                fbl[n] = *(const f16x8*)&Bls[(wc + n * 16 + fr) * 32 + fq * 8];
        }
        #pragma unroll
        for (int m = 0; m < 4; ++m)
            #pragma unroll
            for (int n = 0; n < 4; ++n) {
                acc[m][n] = __builtin_amdgcn_mfma_f32_16x16x32_f16(fa[m], fbh[n], acc[m][n], 0, 0, 0);
                if constexpr (TERMS == 2)
                    acc[m][n] = __builtin_amdgcn_mfma_f32_16x16x32_f16(fa[m], fbl[n], acc[m][n], 0, 0, 0);
            }
        __syncthreads();
    }

    #pragma unroll
    for (int m = 0; m < 4; ++m) {
        const int row = m0 + wr + m * 16 + fq * 4;
        #pragma unroll
        for (int n = 0; n < 4; ++n) {
            const int col = n0 + wc + n * 16 + fr;
            #pragma unroll
            for (int j = 0; j < 4; ++j) {
                const size_t idx = (size_t)(row + j) * N + col;
                float v = acc[m][n][j];
                if (mode == 4) {
                    const float* hv = HVp + (size_t)(row + j) * 16;
                    const float* vv = vBp + (size_t)col * 16;
                    float yv = 0.f;
                    #pragma unroll
                    for (int kk = 0; kk < 16; ++kk) yv = fmaf(hv[kk], vv[kk], yv);
                    const float sg = sigm(yv + bias[col]);
                    v = v + sg * (aux[idx] - v);
                } else if (mode == 3 && z == 0) {
                    v = 0.6065306597126334f * sigm(v + bias[col]);
                }
                C[idx] = v;
            }
        }
    }
}

// fallback-path kernels --------------------------------------------------------
__global__ void wcvt2_h(const float* __restrict__ in0, const float* __restrict__ in1,
                        unsigned short* __restrict__ hi0, unsigned short* __restrict__ hi1,
                        int total8)
{
    int i = blockIdx.x * 256 + threadIdx.x;
    if (i >= total8) return;
    const float* in = (blockIdx.y == 0) ? in0 : in1;
    unsigned short* hi = (blockIdx.y == 0) ? hi0 : hi1;
    const size_t e = (size_t)i * 8;
    float a[8];
    *(float4*)&a[0] = *(const float4*)(in + e);
    *(float4*)&a[4] = *(const float4*)(in + e + 4);
    ushort8 h8;
    #pragma unroll
    for (int j = 0; j < 8; ++j) h8[j] = f2h(a[j]);
    *(ushort8*)(hi + e) = h8;
}

__global__ void mixcvt6_h(const float* __restrict__ in, const float* __restrict__ x_x,
                          unsigned short* __restrict__ oR, unsigned short* __restrict__ oK,
                          unsigned short* __restrict__ ow, unsigned short* __restrict__ oa,
                          unsigned short* __restrict__ og, unsigned short* __restrict__ ov,
                          int T, int D, int total8)
{
    int i = blockIdx.x * 256 + threadIdx.x;
    if (i >= total8) return;
    const size_t e = (size_t)i * 8;
    float a[8];
    *(float4*)&a[0] = *(const float4*)(in + e);
    *(float4*)&a[4] = *(const float4*)(in + e + 4);
    const int m = (int)(e / D);
    const int d = (int)(e % D);
    const int t = m % T;
    float p[8] = {0.f,0.f,0.f,0.f,0.f,0.f,0.f,0.f};
    if (t > 0) {
        *(float4*)&p[0] = *(const float4*)(in + e - D);
        *(float4*)&p[4] = *(const float4*)(in + e - D + 4);
    }
    const float* xxr = x_x + 0 * (size_t)D + d;
    const float* xxw = x_x + 1 * (size_t)D + d;
    const float* xxk = x_x + 2 * (size_t)D + d;
    const float* xxv = x_x + 3 * (size_t)D + d;
    const float* xxa = x_x + 4 * (size_t)D + d;
    const float* xxg = x_x + 5 * (size_t)D + d;
    ushort8 rr, rk, rw, ra, rg, rv;
    #pragma unroll
    for (int j = 0; j < 8; ++j) {
        const float dl = p[j] - a[j];
        rr[j] = f2h(a[j] + dl * xxr[j]);
        rk[j] = f2h(a[j] + dl * xxk[j]);
        rw[j] = f2h(a[j] + dl * xxw[j]);
        ra[j] = f2h(a[j] + dl * xxa[j]);
        rg[j] = f2h(a[j] + dl * xxg[j]);
        rv[j] = f2h(a[j] + dl * xxv[j]);
    }
    *(ushort8*)(oR + e) = rr;
    *(ushort8*)(oK + e) = rk;
    *(ushort8*)(ow + e) = rw;
    *(ushort8*)(oa + e) = ra;
    *(ushort8*)(og + e) = rg;
    *(ushort8*)(ov + e) = rv;
}

__global__ void wcvt_lora(const float* __restrict__ wA, const float* __restrict__ vA,
                          const float* __restrict__ aA, const float* __restrict__ gA,
                          unsigned short* __restrict__ WL, int K)
{
    const int z = blockIdx.y;
    int i = blockIdx.x * 256 + threadIdx.x;
    const size_t e = (size_t)i * 8;
    const int row = (int)(e / K);
    const int col = (int)(e % K);
    const int nv = (z == 0) ? 64 : (z == 1) ? 16 : (z == 2) ? 64 : 128;
    const float* src = (z == 0) ? wA : (z == 1) ? vA : (z == 2) ? aA : gA;
    ushort8 h8;
    if (row < nv) {
        float a[8];
        *(float4*)&a[0] = *(const float4*)(src + (size_t)row * K + col);
        *(float4*)&a[4] = *(const float4*)(src + (size_t)row * K + col + 4);
        #pragma unroll
        for (int j = 0; j < 8; ++j) h8[j] = f2h(a[j]);
    } else {
        #pragma unroll
        for (int j = 0; j < 8; ++j) h8[j] = 0;
    }
    *(ushort8*)(WL + (size_t)z * 128 * K + e) = h8;
}

__global__ __launch_bounds__(256) void lora1_h(
    const unsigned short* __restrict__ Xbase,
    const unsigned short* __restrict__ WL,
    unsigned short* __restrict__ HW16, float* __restrict__ HV,
    unsigned short* __restrict__ HA16, unsigned short* __restrict__ HG16,
    int M, int K, size_t NE)
{
    __shared__ unsigned short As[GBM * 32];
    __shared__ unsigned short Bhs[GBN * 32];
    const int z = blockIdx.z;
    const size_t zofs = (z == 0) ? 0 : (z == 1) ? 3 * NE : (z == 2) ? NE : 2 * NE;
    const unsigned short* Ag = Xbase + zofs;
    const unsigned short* Bg = WL + (size_t)z * 128 * K;
    const int tid = threadIdx.x;
    const int m0 = blockIdx.x * GBM;
    const int wave = tid >> 6, lane = tid & 63;
    const int wr = (wave >> 1) * 64, wc = (wave & 1) * 64;
    const int fr = lane & 15, fq = lane >> 4;

    f32x4 acc[4][4];
    #pragma unroll
    for (int i = 0; i < 4; ++i)
        #pragma unroll
        for (int j = 0; j < 4; ++j)
            acc[i][j] = (f32x4){0.f, 0.f, 0.f, 0.f};

    gemm128_loop(Ag, Bg, As, Bhs, m0, 0, K, tid, acc);

    #pragma unroll
    for (int m = 0; m < 4; ++m) {
        const int row = m0 + wr + m * 16 + fq * 4;
        #pragma unroll
        for (int n = 0; n < 4; ++n) {
            const int col = wc + n * 16 + fr;
            #pragma unroll
            for (int j = 0; j < 4; ++j) {
                const float v = acc[m][n][j];
                const int r = row + j;
                if (z == 0)      { if (col < 64) HW16[(size_t)r * 64 + col] = f2h(tanhf(v)); }
                else if (z == 1) { if (col < 16) HV[(size_t)r * 16 + col] = v; }
                else if (z == 2) { if (col < 64) HA16[(size_t)r * 64 + col] = f2h(v); }
                else             { HG16[(size_t)r * 128 + col] = f2h(sigm(v)); }
            }
        }
    }
}

// per-(b,t,h) wave epilogue
__global__ __launch_bounds__(256) void ka_epi(
    float* __restrict__ Kf, float* __restrict__ A_BV, float* __restrict__ KKo,
    const float* __restrict__ k_k, const float* __restrict__ k_a,
    const float* __restrict__ ab, int total, int H)
{
    int wid = (blockIdx.x << 2) | (threadIdx.x >> 6);
    if (wid >= total) return;
    const int l = threadIdx.x & 63;
    const int h = wid % H;
    const int ch = h * 64 + l;
    const size_t base = (size_t)wid * 64;
    float k0 = Kf[base + l];
    float a = sigm(A_BV[base + l] + ab[ch]);
    float kkr = k0 * k_k[ch];
    float ss = full64(kkr * kkr);
    float inv = 1.f / fmaxf(sqrtf(ss), 1e-12f);
    float kkn = kkr * inv;
    KKo[base + l] = kkn;
    A_BV[base + l] = kkn * a;
    Kf[base + l] = k0 * fmaf(a - 1.f, k_a[ch], 1.f);
}

// -------- scan core --------
#define SCH 16
__device__ __forceinline__ void scan_core(
    float* ldsf, int blk, int l,
    const float* __restrict__ EW, const float* __restrict__ R,
    const float* __restrict__ Kf, const float* __restrict__ Vf,
    const float* __restrict__ KK, const float* __restrict__ BV,
    float* __restrict__ O, int T, int H)
{
    const int bh = blk & 63;
    const int slab = blk >> 6;
    const int b = bh >> 5, h = bh & 31;
    const int vc = l & 7;
    const int g  = l >> 3;
    const int kb = g << 3;
    const int vb0 = slab << 3;
    const size_t step = (size_t)H * 64;
    const size_t base0 = ((size_t)b * T * H + h) * 64;
    const int BUF = 5 * SCH * 64 + SCH * 8;

    auto stage = [&](int c, int buf) {
        float* L = ldsf + buf * BUF;
        const size_t t0 = (size_t)c * SCH;
        const float* gs[5] = {EW, R, Kf, KK, BV};
        #pragma unroll
        for (int s = 0; s < 5; ++s) {
            const float* gp = gs[s];
            #pragma unroll
            for (int j = 0; j < 4; ++j)
                gld16(L + s * SCH * 64 + j * 4 * 64,
                      gp + base0 + (t0 + j * 4 + (l >> 4)) * step + ((l & 15) << 2));
        }
        gld4(L + 5 * SCH * 64,
             Vf + base0 + (t0 + (l >> 3)) * step + vb0 + (l & 7));
        gld4(L + 5 * SCH * 64 + 64,
             Vf + base0 + (t0 + 8 + (l >> 3)) * step + vb0 + (l & 7));
    };

    f32x2 s2[4];
    #pragma unroll
    for (int i = 0; i < 4; ++i) s2[i] = (f32x2){0.f, 0.f};

    struct P { f32x4 e[2], r[2], k[2], q[2], bb[2]; float vv; };
    P PA, PB;
    const int NCH = T / SCH;

    stage(0, 0);
    asm volatile("s_waitcnt vmcnt(0)" ::: "memory");
    __builtin_amdgcn_sched_barrier(0);

    for (int c = 0; c < NCH; ++c) {
        if (c + 1 < NCH) stage(c + 1, (c + 1) & 1);

        const float* L = ldsf + (c & 1) * BUF;
        auto PRE = [&](P& pp, int tt) {
            const int o = tt * 64 + kb;
            #pragma unroll
            for (int j = 0; j < 2; ++j) {
                pp.e[j]  = *(const f32x4*)(L + 0 * SCH * 64 + o + j * 4);
                pp.r[j]  = *(const f32x4*)(L + 1 * SCH * 64 + o + j * 4);
                pp.k[j]  = *(const f32x4*)(L + 2 * SCH * 64 + o + j * 4);
                pp.q[j]  = *(const f32x4*)(L + 3 * SCH * 64 + o + j * 4);
                pp.bb[j] = *(const f32x4*)(L + 4 * SCH * 64 + o + j * 4);
            }
            pp.vv = L[5 * SCH * 64 + tt * 8 + vc];
        };
        auto COMP = [&](const P& pp, int tt) {
            f32x2 sa0 = (f32x2){0.f, 0.f}, sa1 = (f32x2){0.f, 0.f};
            #pragma unroll
            for (int j = 0; j < 2; ++j) {
                const f32x2 elo = __builtin_shufflevector(pp.e[j], pp.e[j], 0, 1);
                const f32x2 ehi = __builtin_shufflevector(pp.e[j], pp.e[j], 2, 3);
                const f32x2 qlo = __builtin_shufflevector(pp.q[j], pp.q[j], 0, 1);
                const f32x2 qhi = __builtin_shufflevector(pp.q[j], pp.q[j], 2, 3);
                s2[2*j]   *= elo;
                s2[2*j+1] *= ehi;
                sa0 += qlo * s2[2*j];
                sa1 += qhi * s2[2*j+1];
            }
            const f32x2 sas = sa0 + sa1;
            float p = -(sas.x + sas.y);
            p = red32(red16(red8(p)));
            const f32x2 p2 = (f32x2){p, p};
            const f32x2 v2 = (f32x2){pp.vv, pp.vv};
            f32x2 o0 = (f32x2){0.f, 0.f}, o1 = (f32x2){0.f, 0.f};
            #pragma unroll
            for (int j = 0; j < 2; ++j) {
                const f32x2 klo = __builtin_shufflevector(pp.k[j], pp.k[j], 0, 1);
                const f32x2 khi = __builtin_shufflevector(pp.k[j], pp.k[j], 2, 3);
                const f32x2 blo = __builtin_shufflevector(pp.bb[j], pp.bb[j], 0, 1);
                const f32x2 bhi = __builtin_shufflevector(pp.bb[j], pp.bb[j], 2, 3);
                const f32x2 rlo = __builtin_shufflevector(pp.r[j], pp.r[j], 0, 1);
                const f32x2 rhi = __builtin_shufflevector(pp.r[j], pp.r[j], 2, 3);
                s2[2*j]   = blo * p2 + (klo * v2 + s2[2*j]);
                s2[2*j+1] = bhi * p2 + (khi * v2 + s2[2*j+1]);
                o0 += rlo * s2[2*j];
                o1 += rhi * s2[2*j+1];
            }
            const f32x2 os = o0 + o1;
            float oo = os.x + os.y;
            oo = red32(red16(red8(oo)));
            if (g == 0)
                O[base0 + (size_t)(c * SCH + tt) * step + vb0 + vc] = oo;
        };

        PRE(PA, 0);
        PRE(PB, 1);
        #pragma unroll
        for (int tt = 0; tt < SCH - 2; tt += 2) {
            COMP(PA, tt);     PRE(PA, tt + 2);
            COMP(PB, tt + 1); PRE(PB, tt + 3);
        }
        COMP(PA, SCH - 2);
        COMP(PB, SCH - 1);

        asm volatile("s_waitcnt vmcnt(0)" ::: "memory");
        __builtin_amdgcn_sched_barrier(0);
    }
}

__global__ __launch_bounds__(64) void rwkv_scan(
    const float* __restrict__ EW, const float* __restrict__ R,
    const float* __restrict__ Kf, const float* __restrict__ Vf,
    const float* __restrict__ KK, const float* __restrict__ BV,
    float* __restrict__ O, int T, int H)
{
    __shared__ float ldsf[2 * (5 * SCH * 64 + SCH * 8)];
    scan_core(ldsf, blockIdx.x, threadIdx.x, EW, R, Kf, Vf, KK, BV, O, T, H);
}

// -------- hybrid: scan + co-scheduled g-gate GEMM + Wo convert --------
__global__ __launch_bounds__(256) void scan_fused(
    const float* __restrict__ EW, const float* __restrict__ R,
    const float* __restrict__ Kf, const float* __restrict__ Vf,
    const float* __restrict__ KK, const float* __restrict__ BV,
    float* __restrict__ O,
    const unsigned short* __restrict__ HG16, const unsigned short* __restrict__ gb16,
    unsigned short* __restrict__ G16,
    const float* __restrict__ Wo, unsigned short* __restrict__ Wo16, int nW8,
    int T, int H, int M, int D)
{
    __shared__ float smemf[2 * (5 * SCH * 64 + SCH * 8)];
    const int bid = blockIdx.x;
    const int tid = threadIdx.x;

    if (bid < 512) {
        if (tid >= 64) return;
        scan_core(smemf, bid, tid, EW, R, Kf, Vf, KK, BV, O, T, H);
        return;
    }
    if (bid < 1024) {                      // g-gate GEMM (K=128, 1-term)
        unsigned short* As  = (unsigned short*)smemf;
        unsigned short* Bhs = As + GBM * 32;
        const int bid2 = bid - 512;
        const int m0 = (bid2 >> 4) * GBM;
        const int n0 = (bid2 & 15) * GBN;
        const int wave = tid >> 6, lane = tid & 63;
        const int wr = (wave >> 1) * 64, wc = (wave & 1) * 64;
        const int fr = lane & 15, fq = lane >> 4;

        f32x4 acc[4][4];
        #pragma unroll
        for (int i = 0; i < 4; ++i)
            #pragma unroll
            for (int j = 0; j < 4; ++j)
                acc[i][j] = (f32x4){0.f, 0.f, 0.f, 0.f};

        gemm128_loop(HG16, gb16, As, Bhs, m0, n0, 128, tid, acc);

        #pragma unroll
        for (int m = 0; m < 4; ++m) {
            const int row = m0 + wr + m * 16 + fq * 4;
            #pragma unroll
            for (int n = 0; n < 4; ++n) {
                const int col = n0 + wc + n * 16 + fr;
                #pragma unroll
                for (int j = 0; j < 4; ++j)
                    G16[(size_t)(row + j) * D + col] = f2h(acc[m][n][j]);
            }
        }
        return;
    }
    // Wo convert
    {
        int i = (bid - 1024) * 256 + tid;
        if (i >= nW8) return;
        const size_t e = (size_t)i * 8;
        float a[8];
        *(float4*)&a[0] = *(const float4*)(Wo + e);
        *(float4*)&a[4] = *(const float4*)(Wo + e + 4);
        ushort8 h8;
        #pragma unroll
        for (int j = 0; j < 8; ++j) h8[j] = f2h(a[j]);
        *(ushort8*)(Wo16 + e) = h8;
    }
}

// GroupNorm + bonus + g-gate; writes ON16 (fp16).
__global__ __launch_bounds__(256) void gn_bonus(
    const float* __restrict__ O, const float* __restrict__ R,
    const float* __restrict__ Kf, const float* __restrict__ Vf,
    const float* __restrict__ G, const unsigned short* __restrict__ G16,
    const float* __restrict__ r_k,
    const float* __restrict__ gn_w, const float* __restrict__ gn_b,
    unsigned short* __restrict__ ON16, int total, int H, float eps)
{
    int wid = (blockIdx.x << 2) | (threadIdx.x >> 6);
    if (wid >= total) return;
    const int l = threadIdx.x & 63;
    const int h = wid % H;
    const int ch = h * 64 + l;
    const size_t base = (size_t)wid * 64;

    const float o = O[base + l];
    const float mu = full64(o) * (1.f / 64.f);
    const float d = o - mu;
    const float ss = full64(d * d);
    const float inv = 1.f / sqrtf(ss * (1.f / 64.f) + eps);
    float on = d * inv * gn_w[ch] + gn_b[ch];

    const float r = R[base + l], k = Kf[base + l], vv = Vf[base + l];
    const float p = full64(r * k * r_k[ch]);
    on = fmaf(p, vv, on);
    const float gg = G16 ? h2f(G16[base + l]) : G[base + l];
    ON16[base + l] = f2h(on * gg);
}

extern "C" void kernel_launch(void* const* d_in, const int* in_sizes, int n_in,
                              void* d_out, int out_size, void* d_ws, size_t ws_size,
                              hipStream_t stream)
{
    const int B = 2, T = 2048, D = 2048, H = 32;
    const int M = B * T;

    const float* hid = (const float*)d_in[0];
    const float* vst = (const float*)d_in[1];
    const float* x_x = (const float*)d_in[2];
    const float* k_k = (const float*)d_in[3];
    const float* k_a = (const float*)d_in[4];
    const float* r_k = (const float*)d_in[5];
    const float* Wr  = (const float*)d_in[6];
    const float* Wk  = (const float*)d_in[7];
    const float* Wv  = (const float*)d_in[8];
    const float* Wo  = (const float*)d_in[9];
    const float* wA  = (const float*)d_in[10];
    const float* wB  = (const float*)d_in[11];
    const float* wb  = (const float*)d_in[12];
    const float* vA  = (const float*)d_in[13];
    const float* vB  = (const float*)d_in[14];
    const float* vb  = (const float*)d_in[15];
    const float* aA  = (const float*)d_in[16];
    const float* aB  = (const float*)d_in[17];
    const float* ab  = (const float*)d_in[18];
    const float* gA  = (const float*)d_in[19];
    const float* gB  = (const float*)d_in[20];
    const float* gnw = (const float*)d_in[21];
    const float* gnb = (const float*)d_in[22];
    float* out = (float*)d_out;

    const size_t NE = (size_t)M * D;   // 8,388,608
    const size_t DD = (size_t)D * D;   // 4,194,304
    const size_t need  = (6 * NE + (size_t)M * 272) * sizeof(float);
    const size_t need2 = (7 * NE + (size_t)M * 272) * sizeof(float);
    if (ws_size < need) return;
    const bool fused = (ws_size >= need2);

    float* W0 = (float*)d_ws;      // R_  (fallback also: WL)
    float* W1 = W0 + NE;           // X2(r,k) -> EW -> ON16
    float* W2 = W1 + NE;           // Kf
    float* W3 = W2 + NE;           // WrH/WkH -> Vf
    float* W4 = W3 + NE;           // [w][a] mixes -> YA -> BV
    float* W5 = W4 + NE;           // [g][v] mixes -> KK
    float* SMALL = W5 + NE;
    unsigned short* HW16 = (unsigned short*)SMALL;
    unsigned short* HA16 = HW16 + (size_t)M * 64;
    unsigned short* HG16 = HA16 + (size_t)M * 64;
    float* HV = (float*)(HG16 + (size_t)M * 128);
    float* W6 = SMALL + (size_t)M * 272;   // fused only

    dim3 blk(256);
    const int nMix = (int)(NE / 8);
    const int nW   = (int)(DD / 8);
    const int nSm  = (int)(D * 64 / 8);
    const int nG   = (int)(D * 128 / 8);
    const float* nf = nullptr;

    unsigned short* X2   = (unsigned short*)W1;
    unsigned short* X4   = (unsigned short*)W4;   // [w][a][g][v] spans W4,W5
    unsigned short* WRK  = (unsigned short*)W3;   // WrH, WkH

    if (fused) {
        unsigned short* W6s  = (unsigned short*)W6;
        unsigned short* G16p = W6s;                        // NE
        unsigned short* WvWo = W6s + NE;                   // DD: WvH then Wo16 (time-shared)
        unsigned short* gb16 = W6s + NE + DD;              // D*128
        unsigned short* wB16 = gb16 + (size_t)D * 128;     // D*64
        unsigned short* aB16 = wB16 + (size_t)D * 64;      // D*64
        unsigned short* WL   = aB16 + (size_t)D * 64;      // 4*128*D  (race fix: was in W0)

        // ---- 1: mega_prep (mixes + LoRA-A pad + six weight converts) ----
        hipLaunchKernelGGL(mega_prep, dim3(4096 + 512 + 3 * 2048 + 64 + 64 + 128), blk, 0, stream,
                           hid, x_x, X2, X2 + NE, X4, X4 + NE, X4 + 2 * NE, X4 + 3 * NE,
                           wA, vA, aA, gA, WL,
                           Wr, Wk, Wv, wB, aB, gB,
                           WRK, WRK + DD, WvWo, wB16, aB16, gb16,
                           T, D, nMix, nW, nSm, nG);

        // ---- 2: mega_b (R/K projections + LoRA stage-1; WL now disjoint from W0) ----
        hipLaunchKernelGGL(mega_b, dim3(1024 + 128), blk, 0, stream,
                           X2, WRK, WRK + DD, W0, W2,
                           X4, WL, HW16, HV, HA16, HG16, M, D, NE);

        // ---- 3: mega_c (V projection + LoRA stage-2; YA -> W4, disjoint from v mix) ----
        hipLaunchKernelGGL(mega_c, dim3(512 + 1024), blk, 0, stream,
                           X4 + 3 * NE, WvWo, W3, HV, vB, vb, vst,
                           HW16, wB16, W1, W4, wb, M, D);

        // ---- 4: ka epilogue (Kf=W2, YA->BV in W4, KK out -> W5) ----
        const int totalW = M * H;
        hipLaunchKernelGGL(ka_epi, dim3(totalW / 4), blk, 0, stream, W2, W4, W5, k_k, k_a, ab, totalW, H);

        // ---- 5: scan + g-gate GEMM + Wo convert (KK=W5, BV=W4) ----
        hipLaunchKernelGGL(scan_fused, dim3(512 + 512 + 2048), blk, 0, stream,
                           W1, W0, W2, W3, W5, W4, out,
                           HG16, gb16, G16p, Wo, WvWo, nW, T, H, M, D);

        // ---- 6: gn_bonus ----
        unsigned short* ON16 = (unsigned short*)W1;
        hipLaunchKernelGGL(gn_bonus, dim3(totalW / 4), blk, 0, stream, out, W0, W2, W3, nf, G16p, r_k, gnw, gnb, ON16, totalW, H, 64.f * 1e-5f);

        // ---- 7: Wo projection ----
        hipLaunchKernelGGL((gemm_h2<1>), dim3(M / GBM, D / GBN, 1), blk, 0, stream,
                           ON16, WvWo, WvWo, out, M, D, D, 0, nf, nf, nf, nf, 0, 0, 0);
    } else {
        // -------- fallback: round-21 sequential path (aliasing safe sequentially) ----
        unsigned short* WL0 = (unsigned short*)W0;
        hipLaunchKernelGGL(mixcvt6_h, dim3(nMix / 256), blk, 0, stream,
                           hid, x_x, X2, X2 + NE, X4, X4 + NE, X4 + 2 * NE, X4 + 3 * NE, T, D, nMix);
        hipLaunchKernelGGL(wcvt_lora, dim3(128, 4), blk, 0, stream, wA, vA, aA, gA, WL0, D);
        hipLaunchKernelGGL(wcvt2_h, dim3(nW / 256, 2), blk, 0, stream, Wr, Wk, WRK, WRK + DD, nW);
        hipLaunchKernelGGL(lora1_h, dim3(M / GBM, 1, 4), blk, 0, stream,
                           X4, WL0, HW16, HV, HA16, HG16, M, D, NE);
        hipLaunchKernelGGL((gemm_h2<1>), dim3(M / GBM, D / GBN, 2), blk, 0, stream,
                           X2, WRK, WRK, W0, M, D, D, 0, nf, nf, nf, nf,
                           NE, DD, 2 * NE);
        unsigned short* WvH = (unsigned short*)W4;
        hipLaunchKernelGGL(wcvt2_h, dim3(nW / 256, 1), blk, 0, stream, Wv, Wv, WvH, WvH, nW);
        hipLaunchKernelGGL((gemm_h2<1>), dim3(M / GBM, D / GBN, 1), blk, 0, stream,
                           X4 + 3 * NE, WvH, WvH, W3, M, D, D, 4, HV, vB, vb, vst, 0, 0, 0);
        unsigned short* wB16 = (unsigned short*)W4;
        unsigned short* aB16 = wB16 + (size_t)D * 64;
        hipLaunchKernelGGL(wcvt2_h, dim3(nSm / 256, 2), blk, 0, stream, wB, aB, wB16, aB16, nSm);
        hipLaunchKernelGGL((gemm_h2<1>), dim3(M / GBM, D / GBN, 2), blk, 0, stream,
                           HW16, wB16, wB16, W1, M, D, 64, 3, nf, nf, wb, nf,
                           (size_t)M * 64, (size_t)D * 64, 4 * NE);
        const int totalW = M * H;
        hipLaunchKernelGGL(ka_epi, dim3(totalW / 4), blk, 0, stream, W2, W5, W4, k_k, k_a, ab, totalW, H);
        hipLaunchKernelGGL(rwkv_scan, dim3(B * H * 8), dim3(64), 0, stream, W1, W0, W2, W3, W4, W5, out, T, H);
        unsigned short* gb16 = (unsigned short*)W5;
        hipLaunchKernelGGL(wcvt2_h, dim3(nG / 256, 1), blk, 0, stream, gB, gB, gb16, gb16, nG);
        hipLaunchKernelGGL((gemm_h2<1>), dim3(M / GBM, D / GBN, 1), blk, 0, stream,
                           HG16, gb16, gb16, W4, M, D, 128, 0, nf, nf, nf, nf, 0, 0, 0);
        unsigned short* ON16 = (unsigned short*)W1;
        hipLaunchKernelGGL(gn_bonus, dim3(totalW / 4), blk, 0, stream, out, W0, W2, W3, W4, (const unsigned short*)nullptr, r_k, gnw, gnb, ON16, totalW, H, 64.f * 1e-5f);
        unsigned short* Wo16 = (unsigned short*)W3;
        hipLaunchKernelGGL(wcvt2_h, dim3(nW / 256, 1), blk, 0, stream, Wo, Wo, Wo16, Wo16, nW);
        hipLaunchKernelGGL((gemm_h2<1>), dim3(M / GBM, D / GBN, 1), blk, 0, stream,
                           ON16, Wo16, Wo16, out, M, D, D, 0, nf, nf, nf, nf, 0, 0, 0);
    }
}

// Round 25
// 829.948 us; speedup vs baseline: 1.1505x; 1.1505x over previous
//
#include <hip/hip_runtime.h>
#include <hip/hip_bf16.h>
#include <math.h>

// RWKV7 attention, round 25 (= round 22 verbatim, the best passing config: 829us):
//  - gemm_rkv: R/K/V projections in one grid.z=3 dispatch (z2 = V with inline-yv
//    mode-4 lerp epilogue).
//  - wcvt_all: six weight converts in one grid.y=6 launch; WvH time-shares Wo16 in W6.
//  - scan_fused: scan (512 blk) + g-gate GEMM (512 blk) + Wo convert (2048 blk).
//  - gn_bonus fp16-out; Wo projection TERMS=1.
// Round-23/24 mega-merges regressed (-125us) and were reverted.

typedef __attribute__((ext_vector_type(8))) unsigned short ushort8;
typedef __attribute__((ext_vector_type(8))) _Float16 f16x8;
typedef __attribute__((ext_vector_type(4))) float f32x4;
typedef __attribute__((ext_vector_type(2))) float f32x2;

__device__ inline unsigned short f2h(float f) {
    _Float16 h = (_Float16)f;
    return __builtin_bit_cast(unsigned short, h);
}
__device__ inline float h2f(unsigned short u) {
    return (float)__builtin_bit_cast(_Float16, u);
}
__device__ inline float sigm(float x) { return 1.f / (1.f + expf(-x)); }

template <int CTRL>
__device__ __forceinline__ float rrot(float x) {
    int xi = __builtin_bit_cast(int, x);
    int yi = __builtin_amdgcn_update_dpp(xi, xi, CTRL, 0xf, 0xf, true);
    return x + __builtin_bit_cast(float, yi);
}
__device__ __forceinline__ float red8(float x)  { return rrot<0x128>(x); }
__device__ __forceinline__ float red16(float x) {
    float b = x;
    asm("" : "+v"(b));
    float a = x;
    asm("v_permlane16_swap_b32 %0, %1" : "+v"(a), "+v"(b));
    return a + b;
}
__device__ __forceinline__ float red32(float x) {
    float b = x;
    asm("" : "+v"(b));
    float a = x;
    asm("v_permlane32_swap_b32 %0, %1" : "+v"(a), "+v"(b));
    return a + b;
}
__device__ __forceinline__ float full64(float x) {
    x = rrot<0x121>(x);
    x = rrot<0x122>(x);
    x = rrot<0x124>(x);
    x = rrot<0x128>(x);
    return red32(red16(x));
}

__device__ __forceinline__ void gld16(void* lds, const void* g)
{
    __builtin_amdgcn_global_load_lds(
        (const __attribute__((address_space(1))) void*)g,
        (__attribute__((address_space(3))) void*)lds, 16, 0, 0);
}
__device__ __forceinline__ void gld4(void* lds, const void* g)
{
    __builtin_amdgcn_global_load_lds(
        (const __attribute__((address_space(1))) void*)g,
        (__attribute__((address_space(3))) void*)lds, 4, 0, 0);
}

// ---------------- all six mixes in one pass (r,k,w,a,g,v) ----------------
__global__ void mixcvt6_h(const float* __restrict__ in, const float* __restrict__ x_x,
                          unsigned short* __restrict__ oR, unsigned short* __restrict__ oK,
                          unsigned short* __restrict__ ow, unsigned short* __restrict__ oa,
                          unsigned short* __restrict__ og, unsigned short* __restrict__ ov,
                          int T, int D, int total8)
{
    int i = blockIdx.x * 256 + threadIdx.x;
    if (i >= total8) return;
    const size_t e = (size_t)i * 8;
    float a[8];
    *(float4*)&a[0] = *(const float4*)(in + e);
    *(float4*)&a[4] = *(const float4*)(in + e + 4);
    const int m = (int)(e / D);
    const int d = (int)(e % D);
    const int t = m % T;
    float p[8] = {0.f,0.f,0.f,0.f,0.f,0.f,0.f,0.f};
    if (t > 0) {
        *(float4*)&p[0] = *(const float4*)(in + e - D);
        *(float4*)&p[4] = *(const float4*)(in + e - D + 4);
    }
    const float* xxr = x_x + 0 * (size_t)D + d;
    const float* xxw = x_x + 1 * (size_t)D + d;
    const float* xxk = x_x + 2 * (size_t)D + d;
    const float* xxv = x_x + 3 * (size_t)D + d;
    const float* xxa = x_x + 4 * (size_t)D + d;
    const float* xxg = x_x + 5 * (size_t)D + d;
    ushort8 rr, rk, rw, ra, rg, rv;
    #pragma unroll
    for (int j = 0; j < 8; ++j) {
        const float dl = p[j] - a[j];
        rr[j] = f2h(a[j] + dl * xxr[j]);
        rk[j] = f2h(a[j] + dl * xxk[j]);
        rw[j] = f2h(a[j] + dl * xxw[j]);
        ra[j] = f2h(a[j] + dl * xxa[j]);
        rg[j] = f2h(a[j] + dl * xxg[j]);
        rv[j] = f2h(a[j] + dl * xxv[j]);
    }
    *(ushort8*)(oR + e) = rr;
    *(ushort8*)(oK + e) = rk;
    *(ushort8*)(ow + e) = rw;
    *(ushort8*)(oa + e) = ra;
    *(ushort8*)(og + e) = rg;
    *(ushort8*)(ov + e) = rv;
}

// weight convert, hi only, two weights per launch (fallback path)
__global__ void wcvt2_h(const float* __restrict__ in0, const float* __restrict__ in1,
                        unsigned short* __restrict__ hi0, unsigned short* __restrict__ hi1,
                        int total8)
{
    int i = blockIdx.x * 256 + threadIdx.x;
    if (i >= total8) return;
    const float* in = (blockIdx.y == 0) ? in0 : in1;
    unsigned short* hi = (blockIdx.y == 0) ? hi0 : hi1;
    const size_t e = (size_t)i * 8;
    float a[8];
    *(float4*)&a[0] = *(const float4*)(in + e);
    *(float4*)&a[4] = *(const float4*)(in + e + 4);
    ushort8 h8;
    #pragma unroll
    for (int j = 0; j < 8; ++j) h8[j] = f2h(a[j]);
    *(ushort8*)(hi + e) = h8;
}

// six weight converts in one launch (fused path): grid.y selects weight
__global__ void wcvt_all(const float* __restrict__ Wr, const float* __restrict__ Wk,
                         const float* __restrict__ Wv, const float* __restrict__ wB,
                         const float* __restrict__ aB, const float* __restrict__ gB,
                         unsigned short* __restrict__ oWr, unsigned short* __restrict__ oWk,
                         unsigned short* __restrict__ oWv, unsigned short* __restrict__ owB,
                         unsigned short* __restrict__ oaB, unsigned short* __restrict__ ogB,
                         int nBig, int nSm, int nG)
{
    const int y = blockIdx.y;
    const float* in;
    unsigned short* hi;
    int lim;
    if (y == 0)      { in = Wr; hi = oWr; lim = nBig; }
    else if (y == 1) { in = Wk; hi = oWk; lim = nBig; }
    else if (y == 2) { in = Wv; hi = oWv; lim = nBig; }
    else if (y == 3) { in = wB; hi = owB; lim = nSm; }
    else if (y == 4) { in = aB; hi = oaB; lim = nSm; }
    else             { in = gB; hi = ogB; lim = nG; }
    int i = blockIdx.x * 256 + threadIdx.x;
    if (i >= lim) return;
    const size_t e = (size_t)i * 8;
    float a[8];
    *(float4*)&a[0] = *(const float4*)(in + e);
    *(float4*)&a[4] = *(const float4*)(in + e + 4);
    ushort8 h8;
    #pragma unroll
    for (int j = 0; j < 8; ++j) h8[j] = f2h(a[j]);
    *(ushort8*)(hi + e) = h8;
}

// LoRA-A weights zero-padded to [4][128][2048] fp16
__global__ void wcvt_lora(const float* __restrict__ wA, const float* __restrict__ vA,
                          const float* __restrict__ aA, const float* __restrict__ gA,
                          unsigned short* __restrict__ WL, int K)
{
    const int z = blockIdx.y;
    int i = blockIdx.x * 256 + threadIdx.x;
    const size_t e = (size_t)i * 8;
    const int row = (int)(e / K);
    const int col = (int)(e % K);
    const int nv = (z == 0) ? 64 : (z == 1) ? 16 : (z == 2) ? 64 : 128;
    const float* src = (z == 0) ? wA : (z == 1) ? vA : (z == 2) ? aA : gA;
    ushort8 h8;
    if (row < nv) {
        float a[8];
        *(float4*)&a[0] = *(const float4*)(src + (size_t)row * K + col);
        *(float4*)&a[4] = *(const float4*)(src + (size_t)row * K + col + 4);
        #pragma unroll
        for (int j = 0; j < 8; ++j) h8[j] = f2h(a[j]);
    } else {
        #pragma unroll
        for (int j = 0; j < 8; ++j) h8[j] = 0;
    }
    *(ushort8*)(WL + (size_t)z * 128 * K + e) = h8;
}

// ---------------- fp16 MFMA GEMM (generic): C[M,N] = A[M,K] @ W[N,K]^T ----------
// mode 0: C=acc. mode 3: z0: C=0.6065*sigm(acc+bias), z1: C=acc.
// mode 4: yv=dot16(HVp[row],vBp[col]); C=lerp(acc,aux,sigm(yv+bias)).
#define GBM 128
#define GBN 128

template <int TERMS>
__global__ __launch_bounds__(256) void gemm_h2(
    const unsigned short* __restrict__ Ag,
    const unsigned short* __restrict__ Bhg, const unsigned short* __restrict__ Blg,
    float* __restrict__ C, int M, int N, int K, int mode,
    const float* __restrict__ HVp, const float* __restrict__ vBp,
    const float* __restrict__ bias, const float* __restrict__ aux,
    size_t sA, size_t sB, size_t sC)
{
    __shared__ unsigned short As[GBM * 32];
    __shared__ unsigned short Bhs[GBN * 32], Bls[GBN * 32];
    const int z = blockIdx.z;
    Ag  += (size_t)z * sA;
    Bhg += (size_t)z * sB;
    Blg += (size_t)z * sB;
    C   += (size_t)z * sC;
    const int tid = threadIdx.x;
    const int m0 = blockIdx.x * GBM;
    const int n0 = blockIdx.y * GBN;
    const int wave = tid >> 6, lane = tid & 63;
    const int wr = (wave >> 1) * 64, wc = (wave & 1) * 64;
    const int fr = lane & 15, fq = lane >> 4;

    f32x4 acc[4][4];
    #pragma unroll
    for (int i = 0; i < 4; ++i)
        #pragma unroll
        for (int j = 0; j < 4; ++j)
            acc[i][j] = (f32x4){0.f, 0.f, 0.f, 0.f};

    const unsigned short* gsrc;
    unsigned short* lbuf;
    int rofs, nld;
    if (wave == 0)      { gsrc = Ag;  lbuf = As;           rofs = m0;      nld = 4; }
    else if (wave == 1) { gsrc = Ag;  lbuf = As + 64 * 32; rofs = m0 + 64; nld = 4; }
    else if (wave == 2) { gsrc = Bhg; lbuf = Bhs;          rofs = n0;      nld = 8; }
    else                { gsrc = Blg; lbuf = Bls;          rofs = n0;      nld = (TERMS == 2) ? 8 : 0; }
    const unsigned short* gbase = gsrc + (size_t)(rofs + (lane >> 2)) * K + ((lane & 3) << 3);

    for (int k0 = 0; k0 < K; k0 += 32) {
        #pragma unroll
        for (int j = 0; j < 8; ++j)
            if (j < nld)
                gld16(lbuf + j * 16 * 32, gbase + (size_t)(j * 16) * K + k0);
        __syncthreads();

        f16x8 fa[4], fbh[4], fbl[4];
        #pragma unroll
        for (int m = 0; m < 4; ++m)
            fa[m] = *(const f16x8*)&As[(wr + m * 16 + fr) * 32 + fq * 8];
        #pragma unroll
        for (int n = 0; n < 4; ++n) {
            fbh[n] = *(const f16x8*)&Bhs[(wc + n * 16 + fr) * 32 + fq * 8];
            if constexpr (TERMS == 2)
                fbl[n] = *(const f16x8*)&Bls[(wc + n * 16 + fr) * 32 + fq * 8];
        }
        #pragma unroll
        for (int m = 0; m < 4; ++m)
            #pragma unroll
            for (int n = 0; n < 4; ++n) {
                acc[m][n] = __builtin_amdgcn_mfma_f32_16x16x32_f16(fa[m], fbh[n], acc[m][n], 0, 0, 0);
                if constexpr (TERMS == 2)
                    acc[m][n] = __builtin_amdgcn_mfma_f32_16x16x32_f16(fa[m], fbl[n], acc[m][n], 0, 0, 0);
            }
        __syncthreads();
    }

    #pragma unroll
    for (int m = 0; m < 4; ++m) {
        const int row = m0 + wr + m * 16 + fq * 4;
        #pragma unroll
        for (int n = 0; n < 4; ++n) {
            const int col = n0 + wc + n * 16 + fr;
            #pragma unroll
            for (int j = 0; j < 4; ++j) {
                const size_t idx = (size_t)(row + j) * N + col;
                float v = acc[m][n][j];
                if (mode == 4) {
                    const float* hv = HVp + (size_t)(row + j) * 16;
                    const float* vv = vBp + (size_t)col * 16;
                    float yv = 0.f;
                    #pragma unroll
                    for (int kk = 0; kk < 16; ++kk) yv = fmaf(hv[kk], vv[kk], yv);
                    const float sg = sigm(yv + bias[col]);
                    v = v + sg * (aux[idx] - v);
                } else if (mode == 3 && z == 0) {
                    v = 0.6065306597126334f * sigm(v + bias[col]);
                }
                C[idx] = v;
            }
        }
    }
}

// ---------------- R/K/V in one dispatch (z: 0=R, 1=K, 2=V with mode-4 epilogue) -------
__global__ __launch_bounds__(256) void gemm_rkv(
    const unsigned short* __restrict__ Xrk,   // [r][k] fp16 (M*K each)
    const unsigned short* __restrict__ Xv,    // v mix fp16
    const unsigned short* __restrict__ Wr16, const unsigned short* __restrict__ Wk16,
    const unsigned short* __restrict__ Wv16,
    float* __restrict__ Cr, float* __restrict__ Ck, float* __restrict__ Cv,
    const float* __restrict__ HVp, const float* __restrict__ vBp,
    const float* __restrict__ vb, const float* __restrict__ vst,
    int M, int N, int K)
{
    __shared__ unsigned short As[GBM * 32];
    __shared__ unsigned short Bhs[GBN * 32];
    const int z = blockIdx.z;
    const unsigned short* Ag = (z == 0) ? Xrk : (z == 1) ? (Xrk + (size_t)M * K) : Xv;
    const unsigned short* Bg = (z == 0) ? Wr16 : (z == 1) ? Wk16 : Wv16;
    float* C = (z == 0) ? Cr : (z == 1) ? Ck : Cv;
    const int tid = threadIdx.x;
    const int m0 = blockIdx.x * GBM;
    const int n0 = blockIdx.y * GBN;
    const int wave = tid >> 6, lane = tid & 63;
    const int wr = (wave >> 1) * 64, wc = (wave & 1) * 64;
    const int fr = lane & 15, fq = lane >> 4;

    f32x4 acc[4][4];
    #pragma unroll
    for (int i = 0; i < 4; ++i)
        #pragma unroll
        for (int j = 0; j < 4; ++j)
            acc[i][j] = (f32x4){0.f, 0.f, 0.f, 0.f};

    const unsigned short* gsrc;
    unsigned short* lbuf;
    int rofs, nld;
    if (wave == 0)      { gsrc = Ag; lbuf = As;           rofs = m0;      nld = 4; }
    else if (wave == 1) { gsrc = Ag; lbuf = As + 64 * 32; rofs = m0 + 64; nld = 4; }
    else if (wave == 2) { gsrc = Bg; lbuf = Bhs;          rofs = n0;      nld = 8; }
    else                { gsrc = Bg; lbuf = Bhs;          rofs = n0;      nld = 0; }
    const unsigned short* gbase = gsrc + (size_t)(rofs + (lane >> 2)) * K + ((lane & 3) << 3);

    for (int k0 = 0; k0 < K; k0 += 32) {
        #pragma unroll
        for (int j = 0; j < 8; ++j)
            if (j < nld)
                gld16(lbuf + j * 16 * 32, gbase + (size_t)(j * 16) * K + k0);
        __syncthreads();

        f16x8 fa[4], fb[4];
        #pragma unroll
        for (int m = 0; m < 4; ++m)
            fa[m] = *(const f16x8*)&As[(wr + m * 16 + fr) * 32 + fq * 8];
        #pragma unroll
        for (int n = 0; n < 4; ++n)
            fb[n] = *(const f16x8*)&Bhs[(wc + n * 16 + fr) * 32 + fq * 8];
        #pragma unroll
        for (int m = 0; m < 4; ++m)
            #pragma unroll
            for (int n = 0; n < 4; ++n)
                acc[m][n] = __builtin_amdgcn_mfma_f32_16x16x32_f16(fa[m], fb[n], acc[m][n], 0, 0, 0);
        __syncthreads();
    }

    #pragma unroll
    for (int m = 0; m < 4; ++m) {
        const int row = m0 + wr + m * 16 + fq * 4;
        #pragma unroll
        for (int n = 0; n < 4; ++n) {
            const int col = n0 + wc + n * 16 + fr;
            #pragma unroll
            for (int j = 0; j < 4; ++j) {
                const size_t idx = (size_t)(row + j) * N + col;
                float v = acc[m][n][j];
                if (z == 2) {
                    const float* hv = HVp + (size_t)(row + j) * 16;
                    const float* vv = vBp + (size_t)col * 16;
                    float yv = 0.f;
                    #pragma unroll
                    for (int kk = 0; kk < 16; ++kk) yv = fmaf(hv[kk], vv[kk], yv);
                    const float sg = sigm(yv + vb[col]);
                    v = v + sg * (vst[idx] - v);
                }
                C[idx] = v;
            }
        }
    }
}

// ---------------- LoRA stage-1 MFMA: z-batched, per-z act epilogue ----------
__global__ __launch_bounds__(256) void lora1_h(
    const unsigned short* __restrict__ Xbase,
    const unsigned short* __restrict__ WL,
    unsigned short* __restrict__ HW16, float* __restrict__ HV,
    unsigned short* __restrict__ HA16, unsigned short* __restrict__ HG16,
    int M, int K, size_t NE)
{
    __shared__ unsigned short As[GBM * 32];
    __shared__ unsigned short Bhs[GBN * 32];
    const int z = blockIdx.z;
    const size_t zofs = (z == 0) ? 0 : (z == 1) ? 3 * NE : (z == 2) ? NE : 2 * NE;  // w,v,a,g
    const unsigned short* Ag = Xbase + zofs;
    const unsigned short* Bg = WL + (size_t)z * 128 * K;
    const int tid = threadIdx.x;
    const int m0 = blockIdx.x * GBM;
    const int wave = tid >> 6, lane = tid & 63;
    const int wr = (wave >> 1) * 64, wc = (wave & 1) * 64;
    const int fr = lane & 15, fq = lane >> 4;

    f32x4 acc[4][4];
    #pragma unroll
    for (int i = 0; i < 4; ++i)
        #pragma unroll
        for (int j = 0; j < 4; ++j)
            acc[i][j] = (f32x4){0.f, 0.f, 0.f, 0.f};

    const unsigned short* gsrc;
    unsigned short* lbuf;
    int rofs, nld;
    if (wave == 0)      { gsrc = Ag; lbuf = As;           rofs = m0;      nld = 4; }
    else if (wave == 1) { gsrc = Ag; lbuf = As + 64 * 32; rofs = m0 + 64; nld = 4; }
    else if (wave == 2) { gsrc = Bg; lbuf = Bhs;          rofs = 0;       nld = 8; }
    else                { gsrc = Bg; lbuf = Bhs;          rofs = 0;       nld = 0; }
    const unsigned short* gbase = gsrc + (size_t)(rofs + (lane >> 2)) * K + ((lane & 3) << 3);

    for (int k0 = 0; k0 < K; k0 += 32) {
        #pragma unroll
        for (int j = 0; j < 8; ++j)
            if (j < nld)
                gld16(lbuf + j * 16 * 32, gbase + (size_t)(j * 16) * K + k0);
        __syncthreads();

        f16x8 fa[4], fb[4];
        #pragma unroll
        for (int m = 0; m < 4; ++m)
            fa[m] = *(const f16x8*)&As[(wr + m * 16 + fr) * 32 + fq * 8];
        #pragma unroll
        for (int n = 0; n < 4; ++n)
            fb[n] = *(const f16x8*)&Bhs[(wc + n * 16 + fr) * 32 + fq * 8];
        #pragma unroll
        for (int m = 0; m < 4; ++m)
            #pragma unroll
            for (int n = 0; n < 4; ++n)
                acc[m][n] = __builtin_amdgcn_mfma_f32_16x16x32_f16(fa[m], fb[n], acc[m][n], 0, 0, 0);
        __syncthreads();
    }

    #pragma unroll
    for (int m = 0; m < 4; ++m) {
        const int row = m0 + wr + m * 16 + fq * 4;
        #pragma unroll
        for (int n = 0; n < 4; ++n) {
            const int col = wc + n * 16 + fr;
            #pragma unroll
            for (int j = 0; j < 4; ++j) {
                const float v = acc[m][n][j];
                const int r = row + j;
                if (z == 0)      { if (col < 64) HW16[(size_t)r * 64 + col] = f2h(tanhf(v)); }
                else if (z == 1) { if (col < 16) HV[(size_t)r * 16 + col] = v; }
                else if (z == 2) { if (col < 64) HA16[(size_t)r * 64 + col] = f2h(v); }
                else             { HG16[(size_t)r * 128 + col] = f2h(sigm(v)); }
            }
        }
    }
}

// per-(b,t,h) wave: a = sigmoid(ya+ab); kk = normalize(k0*k_k); bv = kk*a;
// kfinal = k0*(1+(a-1)*k_a).
__global__ __launch_bounds__(256) void ka_epi(
    float* __restrict__ Kf, float* __restrict__ A_BV, float* __restrict__ KKo,
    const float* __restrict__ k_k, const float* __restrict__ k_a,
    const float* __restrict__ ab, int total, int H)
{
    int wid = (blockIdx.x << 2) | (threadIdx.x >> 6);
    if (wid >= total) return;
    const int l = threadIdx.x & 63;
    const int h = wid % H;
    const int ch = h * 64 + l;
    const size_t base = (size_t)wid * 64;
    float k0 = Kf[base + l];
    float a = sigm(A_BV[base + l] + ab[ch]);
    float kkr = k0 * k_k[ch];
    float ss = full64(kkr * kkr);
    float inv = 1.f / fmaxf(sqrtf(ss), 1e-12f);
    float kkn = kkr * inv;
    KKo[base + l] = kkn;
    A_BV[base + l] = kkn * a;
    Kf[base + l] = k0 * fmaf(a - 1.f, k_a[ch], 1.f);
}

// -------- scan core --------
#define SCH 16
__device__ __forceinline__ void scan_core(
    float* ldsf, int blk, int l,
    const float* __restrict__ EW, const float* __restrict__ R,
    const float* __restrict__ Kf, const float* __restrict__ Vf,
    const float* __restrict__ KK, const float* __restrict__ BV,
    float* __restrict__ O, int T, int H)
{
    const int bh = blk & 63;
    const int slab = blk >> 6;
    const int b = bh >> 5, h = bh & 31;
    const int vc = l & 7;
    const int g  = l >> 3;
    const int kb = g << 3;
    const int vb0 = slab << 3;
    const size_t step = (size_t)H * 64;
    const size_t base0 = ((size_t)b * T * H + h) * 64;
    const int BUF = 5 * SCH * 64 + SCH * 8;

    auto stage = [&](int c, int buf) {
        float* L = ldsf + buf * BUF;
        const size_t t0 = (size_t)c * SCH;
        const float* gs[5] = {EW, R, Kf, KK, BV};
        #pragma unroll
        for (int s = 0; s < 5; ++s) {
            const float* gp = gs[s];
            #pragma unroll
            for (int j = 0; j < 4; ++j)
                gld16(L + s * SCH * 64 + j * 4 * 64,
                      gp + base0 + (t0 + j * 4 + (l >> 4)) * step + ((l & 15) << 2));
        }
        gld4(L + 5 * SCH * 64,
             Vf + base0 + (t0 + (l >> 3)) * step + vb0 + (l & 7));
        gld4(L + 5 * SCH * 64 + 64,
             Vf + base0 + (t0 + 8 + (l >> 3)) * step + vb0 + (l & 7));
    };

    f32x2 s2[4];
    #pragma unroll
    for (int i = 0; i < 4; ++i) s2[i] = (f32x2){0.f, 0.f};

    struct P { f32x4 e[2], r[2], k[2], q[2], bb[2]; float vv; };
    P PA, PB;
    const int NCH = T / SCH;

    stage(0, 0);
    asm volatile("s_waitcnt vmcnt(0)" ::: "memory");
    __builtin_amdgcn_sched_barrier(0);

    for (int c = 0; c < NCH; ++c) {
        if (c + 1 < NCH) stage(c + 1, (c + 1) & 1);

        const float* L = ldsf + (c & 1) * BUF;
        auto PRE = [&](P& pp, int tt) {
            const int o = tt * 64 + kb;
            #pragma unroll
            for (int j = 0; j < 2; ++j) {
                pp.e[j]  = *(const f32x4*)(L + 0 * SCH * 64 + o + j * 4);
                pp.r[j]  = *(const f32x4*)(L + 1 * SCH * 64 + o + j * 4);
                pp.k[j]  = *(const f32x4*)(L + 2 * SCH * 64 + o + j * 4);
                pp.q[j]  = *(const f32x4*)(L + 3 * SCH * 64 + o + j * 4);
                pp.bb[j] = *(const f32x4*)(L + 4 * SCH * 64 + o + j * 4);
            }
            pp.vv = L[5 * SCH * 64 + tt * 8 + vc];
        };
        auto COMP = [&](const P& pp, int tt) {
            f32x2 sa0 = (f32x2){0.f, 0.f}, sa1 = (f32x2){0.f, 0.f};
            #pragma unroll
            for (int j = 0; j < 2; ++j) {
                const f32x2 elo = __builtin_shufflevector(pp.e[j], pp.e[j], 0, 1);
                const f32x2 ehi = __builtin_shufflevector(pp.e[j], pp.e[j], 2, 3);
                const f32x2 qlo = __builtin_shufflevector(pp.q[j], pp.q[j], 0, 1);
                const f32x2 qhi = __builtin_shufflevector(pp.q[j], pp.q[j], 2, 3);
                s2[2*j]   *= elo;
                s2[2*j+1] *= ehi;
                sa0 += qlo * s2[2*j];
                sa1 += qhi * s2[2*j+1];
            }
            const f32x2 sas = sa0 + sa1;
            float p = -(sas.x + sas.y);
            p = red32(red16(red8(p)));
            const f32x2 p2 = (f32x2){p, p};
            const f32x2 v2 = (f32x2){pp.vv, pp.vv};
            f32x2 o0 = (f32x2){0.f, 0.f}, o1 = (f32x2){0.f, 0.f};
            #pragma unroll
            for (int j = 0; j < 2; ++j) {
                const f32x2 klo = __builtin_shufflevector(pp.k[j], pp.k[j], 0, 1);
                const f32x2 khi = __builtin_shufflevector(pp.k[j], pp.k[j], 2, 3);
                const f32x2 blo = __builtin_shufflevector(pp.bb[j], pp.bb[j], 0, 1);
                const f32x2 bhi = __builtin_shufflevector(pp.bb[j], pp.bb[j], 2, 3);
                const f32x2 rlo = __builtin_shufflevector(pp.r[j], pp.r[j], 0, 1);
                const f32x2 rhi = __builtin_shufflevector(pp.r[j], pp.r[j], 2, 3);
                s2[2*j]   = blo * p2 + (klo * v2 + s2[2*j]);
                s2[2*j+1] = bhi * p2 + (khi * v2 + s2[2*j+1]);
                o0 += rlo * s2[2*j];
                o1 += rhi * s2[2*j+1];
            }
            const f32x2 os = o0 + o1;
            float oo = os.x + os.y;
            oo = red32(red16(red8(oo)));
            if (g == 0)
                O[base0 + (size_t)(c * SCH + tt) * step + vb0 + vc] = oo;
        };

        PRE(PA, 0);
        PRE(PB, 1);
        #pragma unroll
        for (int tt = 0; tt < SCH - 2; tt += 2) {
            COMP(PA, tt);     PRE(PA, tt + 2);
            COMP(PB, tt + 1); PRE(PB, tt + 3);
        }
        COMP(PA, SCH - 2);
        COMP(PB, SCH - 1);

        asm volatile("s_waitcnt vmcnt(0)" ::: "memory");
        __builtin_amdgcn_sched_barrier(0);
    }
}

// -------- standalone scan (fallback) --------
__global__ __launch_bounds__(64) void rwkv_scan(
    const float* __restrict__ EW, const float* __restrict__ R,
    const float* __restrict__ Kf, const float* __restrict__ Vf,
    const float* __restrict__ KK, const float* __restrict__ BV,
    float* __restrict__ O, int T, int H)
{
    __shared__ float ldsf[2 * (5 * SCH * 64 + SCH * 8)];
    scan_core(ldsf, blockIdx.x, threadIdx.x, EW, R, Kf, Vf, KK, BV, O, T, H);
}

// -------- hybrid: scan + co-scheduled g-gate GEMM + Wo convert --------
__global__ __launch_bounds__(256) void scan_fused(
    const float* __restrict__ EW, const float* __restrict__ R,
    const float* __restrict__ Kf, const float* __restrict__ Vf,
    const float* __restrict__ KK, const float* __restrict__ BV,
    float* __restrict__ O,
    const unsigned short* __restrict__ HG16, const unsigned short* __restrict__ gb16,
    unsigned short* __restrict__ G16,
    const float* __restrict__ Wo, unsigned short* __restrict__ Wo16, int nW8,
    int T, int H, int M, int D)
{
    __shared__ float smemf[2 * (5 * SCH * 64 + SCH * 8)];
    const int bid = blockIdx.x;
    const int tid = threadIdx.x;

    if (bid < 512) {                       // ---- scan role ----
        if (tid >= 64) return;
        scan_core(smemf, bid, tid, EW, R, Kf, Vf, KK, BV, O, T, H);
        return;
    }
    if (bid < 1024) {                      // ---- g-gate GEMM role (K=128, 1-term) ----
        unsigned short* As  = (unsigned short*)smemf;
        unsigned short* Bhs = As + GBM * 32;
        const int bid2 = bid - 512;
        const int m0 = (bid2 >> 4) * GBM;
        const int n0 = (bid2 & 15) * GBN;
        const int wave = tid >> 6, lane = tid & 63;
        const int wr = (wave >> 1) * 64, wc = (wave & 1) * 64;
        const int fr = lane & 15, fq = lane >> 4;
        const int K = 128;

        f32x4 acc[4][4];
        #pragma unroll
        for (int i = 0; i < 4; ++i)
            #pragma unroll
            for (int j = 0; j < 4; ++j)
                acc[i][j] = (f32x4){0.f, 0.f, 0.f, 0.f};

        const unsigned short* gsrc;
        unsigned short* lbuf;
        int rofs, nld;
        if (wave == 0)      { gsrc = HG16; lbuf = As;           rofs = m0;      nld = 4; }
        else if (wave == 1) { gsrc = HG16; lbuf = As + 64 * 32; rofs = m0 + 64; nld = 4; }
        else if (wave == 2) { gsrc = gb16; lbuf = Bhs;          rofs = n0;      nld = 8; }
        else                { gsrc = gb16; lbuf = Bhs;          rofs = n0;      nld = 0; }
        const unsigned short* gbase = gsrc + (size_t)(rofs + (lane >> 2)) * K + ((lane & 3) << 3);

        for (int k0 = 0; k0 < K; k0 += 32) {
            #pragma unroll
            for (int j = 0; j < 8; ++j)
                if (j < nld)
                    gld16(lbuf + j * 16 * 32, gbase + (size_t)(j * 16) * K + k0);
            __syncthreads();
            f16x8 fa[4], fb[4];
            #pragma unroll
            for (int m = 0; m < 4; ++m)
                fa[m] = *(const f16x8*)&As[(wr + m * 16 + fr) * 32 + fq * 8];
            #pragma unroll
            for (int n = 0; n < 4; ++n)
                fb[n] = *(const f16x8*)&Bhs[(wc + n * 16 + fr) * 32 + fq * 8];
            #pragma unroll
            for (int m = 0; m < 4; ++m)
                #pragma unroll
                for (int n = 0; n < 4; ++n)
                    acc[m][n] = __builtin_amdgcn_mfma_f32_16x16x32_f16(fa[m], fb[n], acc[m][n], 0, 0, 0);
            __syncthreads();
        }
        #pragma unroll
        for (int m = 0; m < 4; ++m) {
            const int row = m0 + wr + m * 16 + fq * 4;
            #pragma unroll
            for (int n = 0; n < 4; ++n) {
                const int col = n0 + wc + n * 16 + fr;
                #pragma unroll
                for (int j = 0; j < 4; ++j)
                    G16[(size_t)(row + j) * D + col] = f2h(acc[m][n][j]);
            }
        }
        return;
    }
    // ---- Wo convert role ----
    {
        int i = (bid - 1024) * 256 + tid;
        if (i >= nW8) return;
        const size_t e = (size_t)i * 8;
        float a[8];
        *(float4*)&a[0] = *(const float4*)(Wo + e);
        *(float4*)&a[4] = *(const float4*)(Wo + e + 4);
        ushort8 h8;
        #pragma unroll
        for (int j = 0; j < 8; ++j) h8[j] = f2h(a[j]);
        *(ushort8*)(Wo16 + e) = h8;
    }
}

// GroupNorm + bonus + g-gate (G f32 or fp16); writes ON16 (fp16).
__global__ __launch_bounds__(256) void gn_bonus(
    const float* __restrict__ O, const float* __restrict__ R,
    const float* __restrict__ Kf, const float* __restrict__ Vf,
    const float* __restrict__ G, const unsigned short* __restrict__ G16,
    const float* __restrict__ r_k,
    const float* __restrict__ gn_w, const float* __restrict__ gn_b,
    unsigned short* __restrict__ ON16, int total, int H, float eps)
{
    int wid = (blockIdx.x << 2) | (threadIdx.x >> 6);
    if (wid >= total) return;
    const int l = threadIdx.x & 63;
    const int h = wid % H;
    const int ch = h * 64 + l;
    const size_t base = (size_t)wid * 64;

    const float o = O[base + l];
    const float mu = full64(o) * (1.f / 64.f);
    const float d = o - mu;
    const float ss = full64(d * d);
    const float inv = 1.f / sqrtf(ss * (1.f / 64.f) + eps);
    float on = d * inv * gn_w[ch] + gn_b[ch];

    const float r = R[base + l], k = Kf[base + l], vv = Vf[base + l];
    const float p = full64(r * k * r_k[ch]);
    on = fmaf(p, vv, on);
    const float gg = G16 ? h2f(G16[base + l]) : G[base + l];
    ON16[base + l] = f2h(on * gg);
}

extern "C" void kernel_launch(void* const* d_in, const int* in_sizes, int n_in,
                              void* d_out, int out_size, void* d_ws, size_t ws_size,
                              hipStream_t stream)
{
    const int B = 2, T = 2048, D = 2048, H = 32;
    const int M = B * T;

    const float* hid = (const float*)d_in[0];
    const float* vst = (const float*)d_in[1];
    const float* x_x = (const float*)d_in[2];
    const float* k_k = (const float*)d_in[3];
    const float* k_a = (const float*)d_in[4];
    const float* r_k = (const float*)d_in[5];
    const float* Wr  = (const float*)d_in[6];
    const float* Wk  = (const float*)d_in[7];
    const float* Wv  = (const float*)d_in[8];
    const float* Wo  = (const float*)d_in[9];
    const float* wA  = (const float*)d_in[10];
    const float* wB  = (const float*)d_in[11];
    const float* wb  = (const float*)d_in[12];
    const float* vA  = (const float*)d_in[13];
    const float* vB  = (const float*)d_in[14];
    const float* vb  = (const float*)d_in[15];
    const float* aA  = (const float*)d_in[16];
    const float* aB  = (const float*)d_in[17];
    const float* ab  = (const float*)d_in[18];
    const float* gA  = (const float*)d_in[19];
    const float* gB  = (const float*)d_in[20];
    const float* gnw = (const float*)d_in[21];
    const float* gnb = (const float*)d_in[22];
    float* out = (float*)d_out;

    const size_t NE = (size_t)M * D;   // 8,388,608
    const size_t DD = (size_t)D * D;   // 4,194,304
    const size_t need  = (6 * NE + (size_t)M * 272) * sizeof(float);
    const size_t need2 = (7 * NE + (size_t)M * 272) * sizeof(float);
    if (ws_size < need) return;
    const bool fused = (ws_size >= need2);

    float* W0 = (float*)d_ws;      // WL pad -> R_
    float* W1 = W0 + NE;           // X2(r,k) -> EW -> ON16
    float* W2 = W1 + NE;           // Kf
    float* W3 = W2 + NE;           // WrH/WkH -> Vf
    float* W4 = W3 + NE;           // [w][a] mixes -> KK
    float* W5 = W4 + NE;           // [g][v] mixes -> YA -> BV
    float* SMALL = W5 + NE;
    unsigned short* HW16 = (unsigned short*)SMALL;
    unsigned short* HA16 = HW16 + (size_t)M * 64;
    unsigned short* HG16 = HA16 + (size_t)M * 64;
    float* HV = (float*)(HG16 + (size_t)M * 128);
    float* W6 = SMALL + (size_t)M * 272;   // fused only

    dim3 blk(256);
    const int nMix = (int)(NE / 8);
    const int nW   = (int)(DD / 8);
    const int nSm  = (int)(D * 64 / 8);
    const int nG   = (int)(D * 128 / 8);
    const float* nf = nullptr;

    unsigned short* X2   = (unsigned short*)W1;
    unsigned short* X4   = (unsigned short*)W4;   // [w][a][g][v] spans W4,W5
    unsigned short* WRK  = (unsigned short*)W3;   // WrH, WkH
    unsigned short* WL   = (unsigned short*)W0;

    // ---- 1: all six mixes ----
    hipLaunchKernelGGL(mixcvt6_h, dim3(nMix / 256), blk, 0, stream,
                       hid, x_x, X2, X2 + NE, X4, X4 + NE, X4 + 2 * NE, X4 + 3 * NE, T, D, nMix);

    // ---- 2: LoRA-A pad convert ----
    hipLaunchKernelGGL(wcvt_lora, dim3(128, 4), blk, 0, stream, wA, vA, aA, gA, WL, D);

    if (fused) {
        unsigned short* W6s  = (unsigned short*)W6;
        unsigned short* G16p = W6s;                        // NE
        unsigned short* WvWo = W6s + NE;                   // DD: WvH then Wo16 (time-shared)
        unsigned short* gb16 = W6s + NE + DD;              // D*128
        unsigned short* wB16 = gb16 + (size_t)D * 128;     // D*64
        unsigned short* aB16 = wB16 + (size_t)D * 64;      // D*64

        // ---- 3: all six weight converts in one launch ----
        hipLaunchKernelGGL(wcvt_all, dim3(nW / 256, 6), blk, 0, stream,
                           Wr, Wk, Wv, wB, aB, gB,
                           WRK, WRK + DD, WvWo, wB16, aB16, gb16, nW, nSm, nG);

        // ---- 4: LoRA stage-1 MFMA ----
        hipLaunchKernelGGL(lora1_h, dim3(M / GBM, 1, 4), blk, 0, stream,
                           X4, WL, HW16, HV, HA16, HG16, M, D, NE);

        // ---- 5: R/K/V in one dispatch (V with inline-yv lerp) ----
        hipLaunchKernelGGL(gemm_rkv, dim3(M / GBM, D / GBN, 3), blk, 0, stream,
                           X2, X4 + 3 * NE, WRK, WRK + DD, WvWo,
                           W0, W2, W3, HV, vB, vb, vst, M, D, D);

        // ---- 6: LoRA stage-2 MFMA (z0: EW -> W1; z1: ya -> W5) ----
        hipLaunchKernelGGL((gemm_h2<1>), dim3(M / GBM, D / GBN, 2), blk, 0, stream,
                           HW16, wB16, wB16, W1, M, D, 64, 3, nf, nf, wb, nf,
                           (size_t)M * 64, (size_t)D * 64, 4 * NE);

        // ---- 7: ka epilogue ----
        const int totalW = M * H;
        hipLaunchKernelGGL(ka_epi, dim3(totalW / 4), blk, 0, stream, W2, W5, W4, k_k, k_a, ab, totalW, H);

        // ---- 8: scan + co-scheduled g-gate GEMM + Wo convert (overwrites WvWo) ----
        hipLaunchKernelGGL(scan_fused, dim3(512 + 512 + 2048), blk, 0, stream,
                           W1, W0, W2, W3, W4, W5, out,
                           HG16, gb16, G16p, Wo, WvWo, nW, T, H, M, D);

        // ---- 9: gn_bonus (G fp16) -> ON16 (W1) ----
        unsigned short* ON16 = (unsigned short*)W1;
        hipLaunchKernelGGL(gn_bonus, dim3(totalW / 4), blk, 0, stream, out, W0, W2, W3, nf, G16p, r_k, gnw, gnb, ON16, totalW, H, 64.f * 1e-5f);

        // ---- 10: Wo projection ----
        hipLaunchKernelGGL((gemm_h2<1>), dim3(M / GBM, D / GBN, 1), blk, 0, stream,
                           ON16, WvWo, WvWo, out, M, D, D, 0, nf, nf, nf, nf, 0, 0, 0);
    } else {
        // -------- fallback: round-21 sequential path --------
        hipLaunchKernelGGL(wcvt2_h, dim3(nW / 256, 2), blk, 0, stream, Wr, Wk, WRK, WRK + DD, nW);
        hipLaunchKernelGGL(lora1_h, dim3(M / GBM, 1, 4), blk, 0, stream,
                           X4, WL, HW16, HV, HA16, HG16, M, D, NE);
        hipLaunchKernelGGL((gemm_h2<1>), dim3(M / GBM, D / GBN, 2), blk, 0, stream,
                           X2, WRK, WRK, W0, M, D, D, 0, nf, nf, nf, nf,
                           NE, DD, 2 * NE);
        unsigned short* WvH = (unsigned short*)W4;
        hipLaunchKernelGGL(wcvt2_h, dim3(nW / 256, 1), blk, 0, stream, Wv, Wv, WvH, WvH, nW);
        hipLaunchKernelGGL((gemm_h2<1>), dim3(M / GBM, D / GBN, 1), blk, 0, stream,
                           X4 + 3 * NE, WvH, WvH, W3, M, D, D, 4, HV, vB, vb, vst, 0, 0, 0);
        unsigned short* wB16 = (unsigned short*)W4;
        unsigned short* aB16 = wB16 + (size_t)D * 64;
        hipLaunchKernelGGL(wcvt2_h, dim3(nSm / 256, 2), blk, 0, stream, wB, aB, wB16, aB16, nSm);
        hipLaunchKernelGGL((gemm_h2<1>), dim3(M / GBM, D / GBN, 2), blk, 0, stream,
                           HW16, wB16, wB16, W1, M, D, 64, 3, nf, nf, wb, nf,
                           (size_t)M * 64, (size_t)D * 64, 4 * NE);
        const int totalW = M * H;
        hipLaunchKernelGGL(ka_epi, dim3(totalW / 4), blk, 0, stream, W2, W5, W4, k_k, k_a, ab, totalW, H);
        hipLaunchKernelGGL(rwkv_scan, dim3(B * H * 8), dim3(64), 0, stream, W1, W0, W2, W3, W4, W5, out, T, H);
        unsigned short* gb16 = (unsigned short*)W5;
        hipLaunchKernelGGL(wcvt2_h, dim3(nG / 256, 1), blk, 0, stream, gB, gB, gb16, gb16, nG);
        hipLaunchKernelGGL((gemm_h2<1>), dim3(M / GBM, D / GBN, 1), blk, 0, stream,
                           HG16, gb16, gb16, W4, M, D, 128, 0, nf, nf, nf, nf, 0, 0, 0);
        unsigned short* ON16 = (unsigned short*)W1;
        hipLaunchKernelGGL(gn_bonus, dim3(totalW / 4), blk, 0, stream, out, W0, W2, W3, W4, (const unsigned short*)nullptr, r_k, gnw, gnb, ON16, totalW, H, 64.f * 1e-5f);
        unsigned short* Wo16 = (unsigned short*)W3;
        hipLaunchKernelGGL(wcvt2_h, dim3(nW / 256, 1), blk, 0, stream, Wo, Wo, Wo16, Wo16, nW);
        hipLaunchKernelGGL((gemm_h2<1>), dim3(M / GBM, D / GBN, 1), blk, 0, stream,
                           ON16, Wo16, Wo16, out, M, D, D, 0, nf, nf, nf, nf, 0, 0, 0);
    }
}